// Round 8
// baseline (337.444 us; speedup 1.0000x reference)
//
#include <hip/hip_runtime.h>

#define D 128
#define NE 16
#define HOPS 3
#define NSUB 4      // sharded sub-lists per node (atomic depth 16 -> 4)
#define SCAP 24     // slots per sub-list (P(Poisson(4)>=24) ~ 1e-12)
#define CAP (NSUB * SCAP)
#define CPAD 32     // counter array stride per node (ints); sub-counter q at +q*8

typedef __attribute__((ext_vector_type(8))) __bf16 bf16x8;
typedef __attribute__((ext_vector_type(4))) __bf16 bf16x4;
typedef __attribute__((ext_vector_type(4))) float f32x4;

#define PK_MASK 0x07FFFFFFu
#define PK_SHIFT 27

// ---------------- fused one-time prep ----------------
// blocks [0, FB)          : sharded slotted CSR fill (one atomic pass)
// blocks [FB, FB+WB)      : weight transpose + bf16 cast (all hops)
// blocks [FB+WB, FB+WB+CB): x fp32 -> bf16 cast
__global__ __launch_bounds__(256) void prep_kernel(
    const int* __restrict__ src, const int* __restrict__ dest,
    const int* __restrict__ classes, int* __restrict__ cnt,
    unsigned int* __restrict__ s_pk, int E, int FB,
    const float* __restrict__ Wsrc, const float* __restrict__ Wdst,
    __bf16* __restrict__ WTs, __bf16* __restrict__ WTd, int WB,
    const float* __restrict__ x, __bf16* __restrict__ xb, int n4, int CB) {
  int b = blockIdx.x;
  int tid = threadIdx.x;
  if (b < FB) {
    int e = b * 256 + tid;
    if (e < E) {
      int d = dest[e];
      int sub = e & (NSUB - 1);
      int p = atomicAdd(&cnt[(size_t)d * CPAD + sub * 8], 1);
      if (p < SCAP)
        s_pk[(size_t)d * CAP + sub * SCAP + p] =
            (unsigned int)src[e] | ((unsigned int)classes[e] << PK_SHIFT);
    }
  } else if (b < FB + WB) {
    int gid = (b - FB) * 256 + tid;            // < HOPS*D*D
    int h = gid >> 14;                          // D*D = 16384
    int rem = gid & 16383;
    int k = rem >> 7, nn = rem & 127;
    size_t o = (size_t)h * 16384 + nn * 128 + k;
    WTs[o] = (__bf16)Wsrc[gid];
    WTd[o] = (__bf16)Wdst[gid];
  } else {
    int i = (b - FB - WB) * 256 + tid;
    if (i < n4) {
      f32x4 v = ((const f32x4*)x)[i];
      bf16x4 o;
      o[0] = (__bf16)v[0]; o[1] = (__bf16)v[1]; o[2] = (__bf16)v[2]; o[3] = (__bf16)v[3];
      ((bf16x4*)xb)[i] = o;
    }
  }
}

// ---------------- fused dual GEMM (bf16 MFMA): s = x@Ws+bs, t = x@Wd+bd ----------------
// BM=128: each wave computes TWO 16-row tiles sharing one set of B fragments
__global__ __launch_bounds__(256) void gemm_dual(const __bf16* __restrict__ xb,
    const __bf16* __restrict__ WTs, const __bf16* __restrict__ WTd,
    const float* __restrict__ bs, const float* __restrict__ bd,
    __bf16* __restrict__ s_b, __bf16* __restrict__ t_b, int n) {
  int w = threadIdx.x >> 6, l = threadIdx.x & 63;
  int l16 = l & 15, q = l >> 4;
  bf16x8 a[2][4];
  #pragma unroll
  for (int rt = 0; rt < 2; ++rt) {
    int rowA = blockIdx.x * 128 + (w + rt * 4) * 16 + l16;
    int rsafe = rowA < n ? rowA : 0;
    #pragma unroll
    for (int ks = 0; ks < 4; ++ks)
      a[rt][ks] = *(const bf16x8*)&xb[(size_t)rsafe * D + ks * 32 + q * 8];
  }
  f32x4 accS[2][8], accT[2][8];
  #pragma unroll
  for (int rt = 0; rt < 2; ++rt)
    #pragma unroll
    for (int n0 = 0; n0 < 8; ++n0) {
      accS[rt][n0] = (f32x4)0.f;
      accT[rt][n0] = (f32x4)0.f;
    }
  #pragma unroll
  for (int n0 = 0; n0 < 8; ++n0) {
    const __bf16* ps = &WTs[(size_t)(n0 * 16 + l16) * D + q * 8];
    const __bf16* pt = &WTd[(size_t)(n0 * 16 + l16) * D + q * 8];
    #pragma unroll
    for (int ks = 0; ks < 4; ++ks) {
      bf16x8 bfs = *(const bf16x8*)(ps + ks * 32);
      bf16x8 bft = *(const bf16x8*)(pt + ks * 32);
      #pragma unroll
      for (int rt = 0; rt < 2; ++rt) {
        accS[rt][n0] = __builtin_amdgcn_mfma_f32_16x16x32_bf16(a[rt][ks], bfs, accS[rt][n0], 0, 0, 0);
        accT[rt][n0] = __builtin_amdgcn_mfma_f32_16x16x32_bf16(a[rt][ks], bft, accT[rt][n0], 0, 0, 0);
      }
    }
  }
  #pragma unroll
  for (int rt = 0; rt < 2; ++rt) {
    int rowD = blockIdx.x * 128 + (w + rt * 4) * 16 + q * 4;
    #pragma unroll
    for (int n0 = 0; n0 < 8; ++n0) {
      int col = n0 * 16 + l16;
      float bS = bs[col], bT = bd[col];
      #pragma unroll
      for (int r = 0; r < 4; ++r) {
        int row = rowD + r;
        if (row < n) {
          s_b[(size_t)row * D + col] = (__bf16)(accS[rt][n0][r] + bS);
          t_b[(size_t)row * D + col] = (__bf16)(accT[rt][n0][r] + bT);
        }
      }
    }
  }
}

// ------- fused aggregate: segment-mean(relu(s[src]+t[n]+ee[cls])) + residual + LayerNorm -------
// one wave per node; quarter q owns sub-list q; up to 4 gathers in flight per quarter
__global__ __launch_bounds__(256) void aggregate_kernel(
    const __bf16* __restrict__ s_b, const __bf16* __restrict__ t_b,
    const float* __restrict__ xin,
    const int* __restrict__ cnt_arr,
    const unsigned int* __restrict__ s_pk,
    const float* __restrict__ ee, const float* __restrict__ gamma,
    const float* __restrict__ beta, float* __restrict__ xout,
    __bf16* __restrict__ xb_out, int write_xb, int n) {
  __shared__ float ee_s[NE * D];
  for (int i = threadIdx.x; i < NE * D; i += 256) ee_s[i] = ee[i];
  __syncthreads();
  int wave = threadIdx.x >> 6;
  int lane = threadIdx.x & 63;
  int node = blockIdx.x * 4 + wave;
  if (node >= n) return;
  int quarter = lane >> 4;
  int l16 = lane & 15;
  int d0 = l16 * 8;
  size_t nbase = (size_t)node * D;
  bf16x8 tvb = *(const bf16x8*)&t_b[nbase + d0];
  float tv[8];
  #pragma unroll
  for (int j = 0; j < 8; ++j) tv[j] = (float)tvb[j];
  f32x4 xlo = *(const f32x4*)&xin[nbase + d0];
  f32x4 xhi = *(const f32x4*)&xin[nbase + d0 + 4];

  int cq = cnt_arr[(size_t)node * CPAD + quarter * 8];
  if (cq > SCAP) cq = SCAP;
  int base = node * CAP + quarter * SCAP;
  float acc[8] = {0.f, 0.f, 0.f, 0.f, 0.f, 0.f, 0.f, 0.f};

#define EDGE_ACC(V, SV)                                                        \
  {                                                                            \
    const float* ep = &ee_s[((V) >> PK_SHIFT) * D + d0];                       \
    f32x4 ea = *(const f32x4*)ep, eb = *(const f32x4*)(ep + 4);                \
    _Pragma("unroll")                                                          \
    for (int j = 0; j < 8; ++j) {                                              \
      float u = (float)(SV)[j] + tv[j] + (j < 4 ? ea[j] : eb[j - 4]);          \
      acc[j] += fmaxf(u, 0.f);                                                 \
    }                                                                          \
  }

  int i = 0;
  for (; i + 3 < cq; i += 4) {
    unsigned int v0 = s_pk[base + i];
    unsigned int v1 = s_pk[base + i + 1];
    unsigned int v2 = s_pk[base + i + 2];
    unsigned int v3 = s_pk[base + i + 3];
    bf16x8 s0 = *(const bf16x8*)&s_b[(size_t)(v0 & PK_MASK) * D + d0];
    bf16x8 s1 = *(const bf16x8*)&s_b[(size_t)(v1 & PK_MASK) * D + d0];
    bf16x8 s2 = *(const bf16x8*)&s_b[(size_t)(v2 & PK_MASK) * D + d0];
    bf16x8 s3 = *(const bf16x8*)&s_b[(size_t)(v3 & PK_MASK) * D + d0];
    EDGE_ACC(v0, s0); EDGE_ACC(v1, s1); EDGE_ACC(v2, s2); EDGE_ACC(v3, s3);
  }
  if (i + 1 < cq) {
    unsigned int v0 = s_pk[base + i];
    unsigned int v1 = s_pk[base + i + 1];
    bf16x8 s0 = *(const bf16x8*)&s_b[(size_t)(v0 & PK_MASK) * D + d0];
    bf16x8 s1 = *(const bf16x8*)&s_b[(size_t)(v1 & PK_MASK) * D + d0];
    EDGE_ACC(v0, s0); EDGE_ACC(v1, s1);
    i += 2;
  }
  if (i < cq) {
    unsigned int v0 = s_pk[base + i];
    bf16x8 s0 = *(const bf16x8*)&s_b[(size_t)(v0 & PK_MASK) * D + d0];
    EDGE_ACC(v0, s0);
  }
#undef EDGE_ACC

  // combine the 4 quarter-accumulators and counts (lanes end with full sums)
  int tot = cq;
  tot += __shfl_xor(tot, 32);
  tot += __shfl_xor(tot, 16);
  #pragma unroll
  for (int j = 0; j < 8; ++j) {
    acc[j] += __shfl_xor(acc[j], 32);
    acc[j] += __shfl_xor(acc[j], 16);
  }
  float invc = tot > 0 ? 1.f / (float)tot : 0.f;
  float y[8];
  #pragma unroll
  for (int j = 0; j < 8; ++j)
    y[j] = acc[j] * invc + (j < 4 ? xlo[j] : xhi[j - 4]);
  float ssum = 0.f;
  #pragma unroll
  for (int j = 0; j < 8; ++j) ssum += y[j];
  #pragma unroll
  for (int off = 8; off > 0; off >>= 1) ssum += __shfl_xor(ssum, off);
  float mu = ssum * (1.f / (float)D);
  float dv[8], vs = 0.f;
  #pragma unroll
  for (int j = 0; j < 8; ++j) { dv[j] = y[j] - mu; vs += dv[j] * dv[j]; }
  #pragma unroll
  for (int off = 8; off > 0; off >>= 1) vs += __shfl_xor(vs, off);
  float inv = rsqrtf(vs * (1.f / (float)D) + 1e-3f);
  if (quarter == 0) {
    f32x4 g0 = *(const f32x4*)&gamma[d0];
    f32x4 g1 = *(const f32x4*)&gamma[d0 + 4];
    f32x4 b0 = *(const f32x4*)&beta[d0];
    f32x4 b1 = *(const f32x4*)&beta[d0 + 4];
    float o[8];
    #pragma unroll
    for (int j = 0; j < 8; ++j)
      o[j] = (j < 4 ? g0[j] : g1[j - 4]) * dv[j] * inv + (j < 4 ? b0[j] : b1[j - 4]);
    f32x4 o0, o1;
    #pragma unroll
    for (int j = 0; j < 4; ++j) { o0[j] = o[j]; o1[j] = o[j + 4]; }
    *(f32x4*)&xout[nbase + d0] = o0;
    *(f32x4*)&xout[nbase + d0 + 4] = o1;
    if (write_xb) {
      bf16x8 ob;
      #pragma unroll
      for (int j = 0; j < 8; ++j) ob[j] = (__bf16)o[j];
      *(bf16x8*)&xb_out[nbase + d0] = ob;
    }
  }
}

extern "C" void kernel_launch(void* const* d_in, const int* in_sizes, int n_in,
                              void* d_out, int out_size, void* d_ws, size_t ws_size,
                              hipStream_t stream) {
  const float* x0     = (const float*)d_in[0];
  const int*   src    = (const int*)d_in[1];
  const int*   dest   = (const int*)d_in[2];
  const int*   cls    = (const int*)d_in[3];
  const float* W_src  = (const float*)d_in[4];
  const float* b_src  = (const float*)d_in[5];
  const float* W_dest = (const float*)d_in[6];
  const float* b_dest = (const float*)d_in[7];
  const float* ee     = (const float*)d_in[8];
  const float* ln_g   = (const float*)d_in[9];
  const float* ln_b   = (const float*)d_in[10];
  float* out = (float*)d_out;

  const int N = in_sizes[0] / D;
  const int E = in_sizes[1];

  char* p = (char*)d_ws;
  __bf16* s_b = (__bf16*)p;   p += (size_t)N * D * sizeof(__bf16);
  __bf16* t_b = (__bf16*)p;   p += (size_t)N * D * sizeof(__bf16);
  __bf16* xb  = (__bf16*)p;   p += (size_t)N * D * sizeof(__bf16);
  __bf16* WTs = (__bf16*)p;   p += (size_t)HOPS * D * D * sizeof(__bf16);
  __bf16* WTd = (__bf16*)p;   p += (size_t)HOPS * D * D * sizeof(__bf16);
  int* cntb   = (int*)p;      p += (size_t)N * CPAD * sizeof(int);
  unsigned int* s_pk = (unsigned int*)p; p += (size_t)N * CAP * sizeof(unsigned int);

  hipMemsetAsync(cntb, 0, (size_t)N * CPAD * sizeof(int), stream);

  const int FB = (E + 255) / 256;
  const int WB = (HOPS * D * D) / 256;
  const int n4 = N * D / 4;
  const int CB = (n4 + 255) / 256;
  prep_kernel<<<FB + WB + CB, 256, 0, stream>>>(
      src, dest, cls, cntb, s_pk, E, FB,
      W_src, W_dest, WTs, WTd, WB,
      x0, xb, n4, CB);

  const float* xin = x0;
  for (int h = 0; h < HOPS; ++h) {
    gemm_dual<<<(N + 127) / 128, 256, 0, stream>>>(
        xb, WTs + (size_t)h * D * D, WTd + (size_t)h * D * D,
        b_src + (size_t)h * D, b_dest + (size_t)h * D, s_b, t_b, N);
    aggregate_kernel<<<(N + 3) / 4, 256, 0, stream>>>(
        s_b, t_b, xin, cntb, s_pk,
        ee + (size_t)h * NE * D, ln_g + (size_t)h * D, ln_b + (size_t)h * D,
        out, xb, (h < HOPS - 1) ? 1 : 0, N);
    xin = out;
  }
}

// Round 9
// 318.806 us; speedup vs baseline: 1.0585x; 1.0585x over previous
//
#include <hip/hip_runtime.h>

#define D 128
#define NE 16
#define HOPS 3
#define NSUB 4      // sharded sub-lists per node (atomic depth 16 -> 4)
#define SCAP 24     // slots per sub-list (P(Poisson(4)>=24) ~ 1e-12)
#define CAP (NSUB * SCAP)
#define CPAD 32     // counter array stride per node (ints); sub-counter q at +q*8

typedef __attribute__((ext_vector_type(8))) __bf16 bf16x8;
typedef __attribute__((ext_vector_type(4))) __bf16 bf16x4;
typedef __attribute__((ext_vector_type(4))) float f32x4;

#define PK_MASK 0x07FFFFFFu
#define PK_SHIFT 27

// ---------------- fused one-time prep ----------------
__global__ __launch_bounds__(256) void prep_kernel(
    const int* __restrict__ src, const int* __restrict__ dest,
    const int* __restrict__ classes, int* __restrict__ cnt,
    unsigned int* __restrict__ s_pk, int E, int FB,
    const float* __restrict__ Wsrc, const float* __restrict__ Wdst,
    __bf16* __restrict__ WTs, __bf16* __restrict__ WTd, int WB,
    const float* __restrict__ x, __bf16* __restrict__ xb, int n4, int CB) {
  int b = blockIdx.x;
  int tid = threadIdx.x;
  if (b < FB) {
    int e = b * 256 + tid;
    if (e < E) {
      int d = dest[e];
      int sub = e & (NSUB - 1);
      int p = atomicAdd(&cnt[(size_t)d * CPAD + sub * 8], 1);
      if (p < SCAP)
        s_pk[(size_t)d * CAP + sub * SCAP + p] =
            (unsigned int)src[e] | ((unsigned int)classes[e] << PK_SHIFT);
    }
  } else if (b < FB + WB) {
    int gid = (b - FB) * 256 + tid;            // < HOPS*D*D
    int h = gid >> 14;                          // D*D = 16384
    int rem = gid & 16383;
    int k = rem >> 7, nn = rem & 127;
    size_t o = (size_t)h * 16384 + nn * 128 + k;
    WTs[o] = (__bf16)Wsrc[gid];
    WTd[o] = (__bf16)Wdst[gid];
  } else {
    int i = (b - FB - WB) * 256 + tid;
    if (i < n4) {
      f32x4 v = ((const f32x4*)x)[i];
      bf16x4 o;
      o[0] = (__bf16)v[0]; o[1] = (__bf16)v[1]; o[2] = (__bf16)v[2]; o[3] = (__bf16)v[3];
      ((bf16x4*)xb)[i] = o;
    }
  }
}

// ---------------- fused dual GEMM (bf16 MFMA): s = x@Ws+bs, t = x@Wd+bd ----------------
__global__ __launch_bounds__(256) void gemm_dual(const __bf16* __restrict__ xb,
    const __bf16* __restrict__ WTs, const __bf16* __restrict__ WTd,
    const float* __restrict__ bs, const float* __restrict__ bd,
    __bf16* __restrict__ s_b, __bf16* __restrict__ t_b, int n) {
  int w = threadIdx.x >> 6, l = threadIdx.x & 63;
  int l16 = l & 15, q = l >> 4;
  bf16x8 a[2][4];
  #pragma unroll
  for (int rt = 0; rt < 2; ++rt) {
    int rowA = blockIdx.x * 128 + (w + rt * 4) * 16 + l16;
    int rsafe = rowA < n ? rowA : 0;
    #pragma unroll
    for (int ks = 0; ks < 4; ++ks)
      a[rt][ks] = *(const bf16x8*)&xb[(size_t)rsafe * D + ks * 32 + q * 8];
  }
  f32x4 accS[2][8], accT[2][8];
  #pragma unroll
  for (int rt = 0; rt < 2; ++rt)
    #pragma unroll
    for (int n0 = 0; n0 < 8; ++n0) {
      accS[rt][n0] = (f32x4)0.f;
      accT[rt][n0] = (f32x4)0.f;
    }
  #pragma unroll
  for (int n0 = 0; n0 < 8; ++n0) {
    const __bf16* ps = &WTs[(size_t)(n0 * 16 + l16) * D + q * 8];
    const __bf16* pt = &WTd[(size_t)(n0 * 16 + l16) * D + q * 8];
    #pragma unroll
    for (int ks = 0; ks < 4; ++ks) {
      bf16x8 bfs = *(const bf16x8*)(ps + ks * 32);
      bf16x8 bft = *(const bf16x8*)(pt + ks * 32);
      #pragma unroll
      for (int rt = 0; rt < 2; ++rt) {
        accS[rt][n0] = __builtin_amdgcn_mfma_f32_16x16x32_bf16(a[rt][ks], bfs, accS[rt][n0], 0, 0, 0);
        accT[rt][n0] = __builtin_amdgcn_mfma_f32_16x16x32_bf16(a[rt][ks], bft, accT[rt][n0], 0, 0, 0);
      }
    }
  }
  #pragma unroll
  for (int rt = 0; rt < 2; ++rt) {
    int rowD = blockIdx.x * 128 + (w + rt * 4) * 16 + q * 4;
    #pragma unroll
    for (int n0 = 0; n0 < 8; ++n0) {
      int col = n0 * 16 + l16;
      float bS = bs[col], bT = bd[col];
      #pragma unroll
      for (int r = 0; r < 4; ++r) {
        int row = rowD + r;
        if (row < n) {
          s_b[(size_t)row * D + col] = (__bf16)(accS[rt][n0][r] + bS);
          t_b[(size_t)row * D + col] = (__bf16)(accT[rt][n0][r] + bT);
        }
      }
    }
  }
}

// ------- fused aggregate: segment-mean(relu(s[src]+t[n]+ee[cls])) + residual + LayerNorm -------
// one wave per node; sharded fill layout, BALANCED consumption:
// quarter q walks concatenated logical index j = q, q+4, ... (round-robin over total degree)
__global__ __launch_bounds__(256) void aggregate_kernel(
    const __bf16* __restrict__ s_b, const __bf16* __restrict__ t_b,
    const float* __restrict__ xin,
    const int* __restrict__ cnt_arr,
    const unsigned int* __restrict__ s_pk,
    const float* __restrict__ ee, const float* __restrict__ gamma,
    const float* __restrict__ beta, float* __restrict__ xout,
    __bf16* __restrict__ xb_out, int write_xb, int n) {
  __shared__ float ee_s[NE * D];
  for (int i = threadIdx.x; i < NE * D; i += 256) ee_s[i] = ee[i];
  __syncthreads();
  int wave = threadIdx.x >> 6;
  int lane = threadIdx.x & 63;
  int node = blockIdx.x * 4 + wave;
  if (node >= n) return;
  int quarter = lane >> 4;
  int l16 = lane & 15;
  int d0 = l16 * 8;
  size_t nbase = (size_t)node * D;
  bf16x8 tvb = *(const bf16x8*)&t_b[nbase + d0];
  float tv[8];
  #pragma unroll
  for (int j = 0; j < 8; ++j) tv[j] = (float)tvb[j];
  f32x4 xlo = *(const f32x4*)&xin[nbase + d0];
  f32x4 xhi = *(const f32x4*)&xin[nbase + d0 + 4];

  const int* cb = &cnt_arr[(size_t)node * CPAD];
  int c0 = min(cb[0], SCAP), c1 = min(cb[8], SCAP);
  int c2 = min(cb[16], SCAP), c3 = min(cb[24], SCAP);
  int p1 = c0, p2 = c0 + c1, p3 = p2 + c2;
  int tot = p3 + c3;
  int base = node * CAP;

  // j (logical concat index) -> physical slot address offset from base
#define SLOT_ADDR(J, AOUT)                                                     \
  {                                                                            \
    int s_ = ((J) >= p1) + ((J) >= p2) + ((J) >= p3);                          \
    int pofs_ = s_ == 0 ? 0 : (s_ == 1 ? p1 : (s_ == 2 ? p2 : p3));            \
    (AOUT) = s_ * SCAP + ((J) - pofs_);                                        \
  }

#define EDGE_ACC(V, SV)                                                        \
  {                                                                            \
    const float* ep = &ee_s[((V) >> PK_SHIFT) * D + d0];                       \
    f32x4 ea = *(const f32x4*)ep, eb = *(const f32x4*)(ep + 4);                \
    _Pragma("unroll")                                                          \
    for (int j = 0; j < 8; ++j) {                                              \
      float u = (float)(SV)[j] + tv[j] + (j < 4 ? ea[j] : eb[j - 4]);          \
      acc[j] += fmaxf(u, 0.f);                                                 \
    }                                                                          \
  }

  float acc[8] = {0.f, 0.f, 0.f, 0.f, 0.f, 0.f, 0.f, 0.f};
  int j = quarter;
  // 4 edges in flight per quarter (16 gathers/wave)
  for (; j + 12 < tot; j += 16) {
    int a0, a1, a2, a3;
    SLOT_ADDR(j, a0); SLOT_ADDR(j + 4, a1); SLOT_ADDR(j + 8, a2); SLOT_ADDR(j + 12, a3);
    unsigned int v0 = s_pk[base + a0];
    unsigned int v1 = s_pk[base + a1];
    unsigned int v2 = s_pk[base + a2];
    unsigned int v3 = s_pk[base + a3];
    bf16x8 s0 = *(const bf16x8*)&s_b[(size_t)(v0 & PK_MASK) * D + d0];
    bf16x8 s1 = *(const bf16x8*)&s_b[(size_t)(v1 & PK_MASK) * D + d0];
    bf16x8 s2 = *(const bf16x8*)&s_b[(size_t)(v2 & PK_MASK) * D + d0];
    bf16x8 s3 = *(const bf16x8*)&s_b[(size_t)(v3 & PK_MASK) * D + d0];
    EDGE_ACC(v0, s0); EDGE_ACC(v1, s1); EDGE_ACC(v2, s2); EDGE_ACC(v3, s3);
  }
  for (; j < tot; j += 4) {
    int a0;
    SLOT_ADDR(j, a0);
    unsigned int v0 = s_pk[base + a0];
    bf16x8 s0 = *(const bf16x8*)&s_b[(size_t)(v0 & PK_MASK) * D + d0];
    EDGE_ACC(v0, s0);
  }
#undef EDGE_ACC
#undef SLOT_ADDR

  // combine the 4 quarter-accumulators (lanes end with full sums)
  #pragma unroll
  for (int jj = 0; jj < 8; ++jj) {
    acc[jj] += __shfl_xor(acc[jj], 32);
    acc[jj] += __shfl_xor(acc[jj], 16);
  }
  float invc = tot > 0 ? 1.f / (float)tot : 0.f;
  float y[8];
  #pragma unroll
  for (int jj = 0; jj < 8; ++jj)
    y[jj] = acc[jj] * invc + (jj < 4 ? xlo[jj] : xhi[jj - 4]);
  float ssum = 0.f;
  #pragma unroll
  for (int jj = 0; jj < 8; ++jj) ssum += y[jj];
  #pragma unroll
  for (int off = 8; off > 0; off >>= 1) ssum += __shfl_xor(ssum, off);
  float mu = ssum * (1.f / (float)D);
  float dv[8], vs = 0.f;
  #pragma unroll
  for (int jj = 0; jj < 8; ++jj) { dv[jj] = y[jj] - mu; vs += dv[jj] * dv[jj]; }
  #pragma unroll
  for (int off = 8; off > 0; off >>= 1) vs += __shfl_xor(vs, off);
  float inv = rsqrtf(vs * (1.f / (float)D) + 1e-3f);
  if (quarter == 0) {
    f32x4 g0 = *(const f32x4*)&gamma[d0];
    f32x4 g1 = *(const f32x4*)&gamma[d0 + 4];
    f32x4 b0 = *(const f32x4*)&beta[d0];
    f32x4 b1 = *(const f32x4*)&beta[d0 + 4];
    float o[8];
    #pragma unroll
    for (int jj = 0; jj < 8; ++jj)
      o[jj] = (jj < 4 ? g0[jj] : g1[jj - 4]) * dv[jj] * inv + (jj < 4 ? b0[jj] : b1[jj - 4]);
    f32x4 o0, o1;
    #pragma unroll
    for (int jj = 0; jj < 4; ++jj) { o0[jj] = o[jj]; o1[jj] = o[jj + 4]; }
    *(f32x4*)&xout[nbase + d0] = o0;
    *(f32x4*)&xout[nbase + d0 + 4] = o1;
    if (write_xb) {
      bf16x8 ob;
      #pragma unroll
      for (int jj = 0; jj < 8; ++jj) ob[jj] = (__bf16)o[jj];
      *(bf16x8*)&xb_out[nbase + d0] = ob;
    }
  }
}

extern "C" void kernel_launch(void* const* d_in, const int* in_sizes, int n_in,
                              void* d_out, int out_size, void* d_ws, size_t ws_size,
                              hipStream_t stream) {
  const float* x0     = (const float*)d_in[0];
  const int*   src    = (const int*)d_in[1];
  const int*   dest   = (const int*)d_in[2];
  const int*   cls    = (const int*)d_in[3];
  const float* W_src  = (const float*)d_in[4];
  const float* b_src  = (const float*)d_in[5];
  const float* W_dest = (const float*)d_in[6];
  const float* b_dest = (const float*)d_in[7];
  const float* ee     = (const float*)d_in[8];
  const float* ln_g   = (const float*)d_in[9];
  const float* ln_b   = (const float*)d_in[10];
  float* out = (float*)d_out;

  const int N = in_sizes[0] / D;
  const int E = in_sizes[1];

  char* p = (char*)d_ws;
  __bf16* s_b = (__bf16*)p;   p += (size_t)N * D * sizeof(__bf16);
  __bf16* t_b = (__bf16*)p;   p += (size_t)N * D * sizeof(__bf16);
  __bf16* xb  = (__bf16*)p;   p += (size_t)N * D * sizeof(__bf16);
  __bf16* WTs = (__bf16*)p;   p += (size_t)HOPS * D * D * sizeof(__bf16);
  __bf16* WTd = (__bf16*)p;   p += (size_t)HOPS * D * D * sizeof(__bf16);
  int* cntb   = (int*)p;      p += (size_t)N * CPAD * sizeof(int);
  unsigned int* s_pk = (unsigned int*)p; p += (size_t)N * CAP * sizeof(unsigned int);

  hipMemsetAsync(cntb, 0, (size_t)N * CPAD * sizeof(int), stream);

  const int FB = (E + 255) / 256;
  const int WB = (HOPS * D * D) / 256;
  const int n4 = N * D / 4;
  const int CB = (n4 + 255) / 256;
  prep_kernel<<<FB + WB + CB, 256, 0, stream>>>(
      src, dest, cls, cntb, s_pk, E, FB,
      W_src, W_dest, WTs, WTd, WB,
      x0, xb, n4, CB);

  const float* xin = x0;
  for (int h = 0; h < HOPS; ++h) {
    gemm_dual<<<(N + 127) / 128, 256, 0, stream>>>(
        xb, WTs + (size_t)h * D * D, WTd + (size_t)h * D * D,
        b_src + (size_t)h * D, b_dest + (size_t)h * D, s_b, t_b, N);
    aggregate_kernel<<<(N + 3) / 4, 256, 0, stream>>>(
        s_b, t_b, xin, cntb, s_pk,
        ee + (size_t)h * NE * D, ln_g + (size_t)h * D, ln_b + (size_t)h * D,
        out, xb, (h < HOPS - 1) ? 1 : 0, N);
    xin = out;
  }
}

// Round 10
// 301.202 us; speedup vs baseline: 1.1203x; 1.0584x over previous
//
#include <hip/hip_runtime.h>

#define D 128
#define NE 16
#define HOPS 3
#define NSUB 4      // sharded sub-lists per node (fill-side atomic depth 16 -> 4)
#define SCAP 24     // slots per sub-list (P(Poisson(4)>=24) ~ 1e-12)
#define CAP (NSUB * SCAP)
#define CPAD 32     // counter array stride per node (ints); sub-counter q at +q*8

typedef __attribute__((ext_vector_type(8))) __bf16 bf16x8;
typedef __attribute__((ext_vector_type(4))) __bf16 bf16x4;
typedef __attribute__((ext_vector_type(4))) float f32x4;

#define PK_MASK 0x07FFFFFFu
#define PK_SHIFT 27

// ---------------- fused one-time prep ----------------
// blocks [0, FB)          : sharded slotted CSR fill (one atomic pass)
// blocks [FB, FB+WB)      : weight transpose + bf16 cast (all hops)
// blocks [FB+WB, FB+WB+CB): x fp32 -> bf16 cast
__global__ __launch_bounds__(256) void prep_kernel(
    const int* __restrict__ src, const int* __restrict__ dest,
    const int* __restrict__ classes, int* __restrict__ cnt,
    unsigned int* __restrict__ raw, int E, int FB,
    const float* __restrict__ Wsrc, const float* __restrict__ Wdst,
    __bf16* __restrict__ WTs, __bf16* __restrict__ WTd, int WB,
    const float* __restrict__ x, __bf16* __restrict__ xb, int n4, int CB) {
  int b = blockIdx.x;
  int tid = threadIdx.x;
  if (b < FB) {
    int e = b * 256 + tid;
    if (e < E) {
      int d = dest[e];
      int sub = e & (NSUB - 1);
      int p = atomicAdd(&cnt[(size_t)d * CPAD + sub * 8], 1);
      if (p < SCAP)
        raw[(size_t)d * CAP + sub * SCAP + p] =
            (unsigned int)src[e] | ((unsigned int)classes[e] << PK_SHIFT);
    }
  } else if (b < FB + WB) {
    int gid = (b - FB) * 256 + tid;            // < HOPS*D*D
    int h = gid >> 14;                          // D*D = 16384
    int rem = gid & 16383;
    int k = rem >> 7, nn = rem & 127;
    size_t o = (size_t)h * 16384 + nn * 128 + k;
    WTs[o] = (__bf16)Wsrc[gid];
    WTd[o] = (__bf16)Wdst[gid];
  } else {
    int i = (b - FB - WB) * 256 + tid;
    if (i < n4) {
      f32x4 v = ((const f32x4*)x)[i];
      bf16x4 o;
      o[0] = (__bf16)v[0]; o[1] = (__bf16)v[1]; o[2] = (__bf16)v[2]; o[3] = (__bf16)v[3];
      ((bf16x4*)xb)[i] = o;
    }
  }
}

// ---------------- compact: merge 4 sub-lists -> contiguous per-node list (once) ----------------
// one wave per node; prefix/select logic paid ONCE per edge instead of per-hop
__global__ __launch_bounds__(256) void compact_kernel(
    const int* __restrict__ cnt, const unsigned int* __restrict__ raw,
    unsigned int* __restrict__ pk, int* __restrict__ totc, int n) {
  int wave = threadIdx.x >> 6, lane = threadIdx.x & 63;
  int node = blockIdx.x * 4 + wave;
  if (node >= n) return;
  const int* cb = &cnt[(size_t)node * CPAD];
  int c0 = min(cb[0], SCAP), c1 = min(cb[8], SCAP);
  int c2 = min(cb[16], SCAP), c3 = min(cb[24], SCAP);
  int p1 = c0, p2 = c0 + c1, p3 = p2 + c2, tot = p3 + c3;
  if (lane == 0) totc[node] = tot;
  size_t rbase = (size_t)node * CAP;
  for (int j = lane; j < tot; j += 64) {
    int s_ = (j >= p1) + (j >= p2) + (j >= p3);
    int pofs = s_ == 0 ? 0 : (s_ == 1 ? p1 : (s_ == 2 ? p2 : p3));
    pk[rbase + j] = raw[rbase + s_ * SCAP + (j - pofs)];
  }
}

// ---------------- fused dual GEMM (bf16 MFMA): s = x@Ws+bs, t = x@Wd+bd ----------------
__global__ __launch_bounds__(256) void gemm_dual(const __bf16* __restrict__ xb,
    const __bf16* __restrict__ WTs, const __bf16* __restrict__ WTd,
    const float* __restrict__ bs, const float* __restrict__ bd,
    __bf16* __restrict__ s_b, __bf16* __restrict__ t_b, int n) {
  int w = threadIdx.x >> 6, l = threadIdx.x & 63;
  int l16 = l & 15, q = l >> 4;
  bf16x8 a[2][4];
  #pragma unroll
  for (int rt = 0; rt < 2; ++rt) {
    int rowA = blockIdx.x * 128 + (w + rt * 4) * 16 + l16;
    int rsafe = rowA < n ? rowA : 0;
    #pragma unroll
    for (int ks = 0; ks < 4; ++ks)
      a[rt][ks] = *(const bf16x8*)&xb[(size_t)rsafe * D + ks * 32 + q * 8];
  }
  f32x4 accS[2][8], accT[2][8];
  #pragma unroll
  for (int rt = 0; rt < 2; ++rt)
    #pragma unroll
    for (int n0 = 0; n0 < 8; ++n0) {
      accS[rt][n0] = (f32x4)0.f;
      accT[rt][n0] = (f32x4)0.f;
    }
  #pragma unroll
  for (int n0 = 0; n0 < 8; ++n0) {
    const __bf16* ps = &WTs[(size_t)(n0 * 16 + l16) * D + q * 8];
    const __bf16* pt = &WTd[(size_t)(n0 * 16 + l16) * D + q * 8];
    #pragma unroll
    for (int ks = 0; ks < 4; ++ks) {
      bf16x8 bfs = *(const bf16x8*)(ps + ks * 32);
      bf16x8 bft = *(const bf16x8*)(pt + ks * 32);
      #pragma unroll
      for (int rt = 0; rt < 2; ++rt) {
        accS[rt][n0] = __builtin_amdgcn_mfma_f32_16x16x32_bf16(a[rt][ks], bfs, accS[rt][n0], 0, 0, 0);
        accT[rt][n0] = __builtin_amdgcn_mfma_f32_16x16x32_bf16(a[rt][ks], bft, accT[rt][n0], 0, 0, 0);
      }
    }
  }
  #pragma unroll
  for (int rt = 0; rt < 2; ++rt) {
    int rowD = blockIdx.x * 128 + (w + rt * 4) * 16 + q * 4;
    #pragma unroll
    for (int n0 = 0; n0 < 8; ++n0) {
      int col = n0 * 16 + l16;
      float bS = bs[col], bT = bd[col];
      #pragma unroll
      for (int r = 0; r < 4; ++r) {
        int row = rowD + r;
        if (row < n) {
          s_b[(size_t)row * D + col] = (__bf16)(accS[rt][n0][r] + bS);
          t_b[(size_t)row * D + col] = (__bf16)(accT[rt][n0][r] + bT);
        }
      }
    }
  }
}

// ------- fused aggregate: segment-mean(relu(s[src]+t[n]+ee[cls])) + residual + LayerNorm -------
// one wave per node; contiguous compacted list; quarter q walks j = q, q+4, ...;
// 4 gathers in flight per quarter (16/wave); residual read from bf16 xb (own row, in-place safe)
__global__ __launch_bounds__(256) void aggregate_kernel(
    const __bf16* __restrict__ s_b, const __bf16* __restrict__ t_b,
    __bf16* xb,                    // residual in (bf16) and next-hop x out; same row per thread
    const int* __restrict__ totc,
    const unsigned int* __restrict__ pk,
    const float* __restrict__ ee, const float* __restrict__ gamma,
    const float* __restrict__ beta, float* __restrict__ xout,
    int write_xb, int n) {
  __shared__ float ee_s[NE * D];
  for (int i = threadIdx.x; i < NE * D; i += 256) ee_s[i] = ee[i];
  __syncthreads();
  int wave = threadIdx.x >> 6;
  int lane = threadIdx.x & 63;
  int node = blockIdx.x * 4 + wave;
  if (node >= n) return;
  int quarter = lane >> 4;
  int l16 = lane & 15;
  int d0 = l16 * 8;
  size_t nbase = (size_t)node * D;
  bf16x8 tvb = *(const bf16x8*)&t_b[nbase + d0];
  float tv[8];
  #pragma unroll
  for (int j = 0; j < 8; ++j) tv[j] = (float)tvb[j];
  bf16x8 xvb = *(const bf16x8*)&xb[nbase + d0];
  float xr[8];
  #pragma unroll
  for (int j = 0; j < 8; ++j) xr[j] = (float)xvb[j];

  int tot = totc[node];
  int base = node * CAP;
  float acc[8] = {0.f, 0.f, 0.f, 0.f, 0.f, 0.f, 0.f, 0.f};

#define EDGE_ACC(V, SV)                                                        \
  {                                                                            \
    const float* ep = &ee_s[((V) >> PK_SHIFT) * D + d0];                       \
    f32x4 ea = *(const f32x4*)ep, eb = *(const f32x4*)(ep + 4);                \
    _Pragma("unroll")                                                          \
    for (int j = 0; j < 8; ++j) {                                              \
      float u = (float)(SV)[j] + tv[j] + (j < 4 ? ea[j] : eb[j - 4]);          \
      acc[j] += fmaxf(u, 0.f);                                                 \
    }                                                                          \
  }

  int j = quarter;
  for (; j + 12 < tot; j += 16) {
    unsigned int v0 = pk[base + j];
    unsigned int v1 = pk[base + j + 4];
    unsigned int v2 = pk[base + j + 8];
    unsigned int v3 = pk[base + j + 12];
    bf16x8 s0 = *(const bf16x8*)&s_b[(size_t)(v0 & PK_MASK) * D + d0];
    bf16x8 s1 = *(const bf16x8*)&s_b[(size_t)(v1 & PK_MASK) * D + d0];
    bf16x8 s2 = *(const bf16x8*)&s_b[(size_t)(v2 & PK_MASK) * D + d0];
    bf16x8 s3 = *(const bf16x8*)&s_b[(size_t)(v3 & PK_MASK) * D + d0];
    EDGE_ACC(v0, s0); EDGE_ACC(v1, s1); EDGE_ACC(v2, s2); EDGE_ACC(v3, s3);
  }
  for (; j < tot; j += 4) {
    unsigned int v0 = pk[base + j];
    bf16x8 s0 = *(const bf16x8*)&s_b[(size_t)(v0 & PK_MASK) * D + d0];
    EDGE_ACC(v0, s0);
  }
#undef EDGE_ACC

  // combine the 4 quarter-accumulators (lanes end with full sums)
  #pragma unroll
  for (int jj = 0; jj < 8; ++jj) {
    acc[jj] += __shfl_xor(acc[jj], 32);
    acc[jj] += __shfl_xor(acc[jj], 16);
  }
  float invc = tot > 0 ? 1.f / (float)tot : 0.f;
  float y[8];
  #pragma unroll
  for (int jj = 0; jj < 8; ++jj)
    y[jj] = acc[jj] * invc + xr[jj];
  float ssum = 0.f;
  #pragma unroll
  for (int jj = 0; jj < 8; ++jj) ssum += y[jj];
  #pragma unroll
  for (int off = 8; off > 0; off >>= 1) ssum += __shfl_xor(ssum, off);
  float mu = ssum * (1.f / (float)D);
  float dv[8], vs = 0.f;
  #pragma unroll
  for (int jj = 0; jj < 8; ++jj) { dv[jj] = y[jj] - mu; vs += dv[jj] * dv[jj]; }
  #pragma unroll
  for (int off = 8; off > 0; off >>= 1) vs += __shfl_xor(vs, off);
  float inv = rsqrtf(vs * (1.f / (float)D) + 1e-3f);
  if (quarter == 0) {
    f32x4 g0 = *(const f32x4*)&gamma[d0];
    f32x4 g1 = *(const f32x4*)&gamma[d0 + 4];
    f32x4 b0 = *(const f32x4*)&beta[d0];
    f32x4 b1 = *(const f32x4*)&beta[d0 + 4];
    float o[8];
    #pragma unroll
    for (int jj = 0; jj < 8; ++jj)
      o[jj] = (jj < 4 ? g0[jj] : g1[jj - 4]) * dv[jj] * inv + (jj < 4 ? b0[jj] : b1[jj - 4]);
    f32x4 o0, o1;
    #pragma unroll
    for (int jj = 0; jj < 4; ++jj) { o0[jj] = o[jj]; o1[jj] = o[jj + 4]; }
    *(f32x4*)&xout[nbase + d0] = o0;
    *(f32x4*)&xout[nbase + d0 + 4] = o1;
    if (write_xb) {
      bf16x8 ob;
      #pragma unroll
      for (int jj = 0; jj < 8; ++jj) ob[jj] = (__bf16)o[jj];
      *(bf16x8*)&xb[nbase + d0] = ob;
    }
  }
}

extern "C" void kernel_launch(void* const* d_in, const int* in_sizes, int n_in,
                              void* d_out, int out_size, void* d_ws, size_t ws_size,
                              hipStream_t stream) {
  const float* x0     = (const float*)d_in[0];
  const int*   src    = (const int*)d_in[1];
  const int*   dest   = (const int*)d_in[2];
  const int*   cls    = (const int*)d_in[3];
  const float* W_src  = (const float*)d_in[4];
  const float* b_src  = (const float*)d_in[5];
  const float* W_dest = (const float*)d_in[6];
  const float* b_dest = (const float*)d_in[7];
  const float* ee     = (const float*)d_in[8];
  const float* ln_g   = (const float*)d_in[9];
  const float* ln_b   = (const float*)d_in[10];
  float* out = (float*)d_out;

  const int N = in_sizes[0] / D;
  const int E = in_sizes[1];

  char* p = (char*)d_ws;
  __bf16* s_b = (__bf16*)p;   p += (size_t)N * D * sizeof(__bf16);
  __bf16* t_b = (__bf16*)p;   p += (size_t)N * D * sizeof(__bf16);
  __bf16* xb  = (__bf16*)p;   p += (size_t)N * D * sizeof(__bf16);
  __bf16* WTs = (__bf16*)p;   p += (size_t)HOPS * D * D * sizeof(__bf16);
  __bf16* WTd = (__bf16*)p;   p += (size_t)HOPS * D * D * sizeof(__bf16);
  int* cntb   = (int*)p;      p += (size_t)N * CPAD * sizeof(int);
  unsigned int* raw = (unsigned int*)p; p += (size_t)N * CAP * sizeof(unsigned int);
  unsigned int* pk  = (unsigned int*)p; p += (size_t)N * CAP * sizeof(unsigned int);
  int* totc   = (int*)p;      p += (size_t)N * sizeof(int);

  hipMemsetAsync(cntb, 0, (size_t)N * CPAD * sizeof(int), stream);

  const int FB = (E + 255) / 256;
  const int WB = (HOPS * D * D) / 256;
  const int n4 = N * D / 4;
  const int CB = (n4 + 255) / 256;
  prep_kernel<<<FB + WB + CB, 256, 0, stream>>>(
      src, dest, cls, cntb, raw, E, FB,
      W_src, W_dest, WTs, WTd, WB,
      x0, xb, n4, CB);

  compact_kernel<<<(N + 3) / 4, 256, 0, stream>>>(cntb, raw, pk, totc, N);

  for (int h = 0; h < HOPS; ++h) {
    gemm_dual<<<(N + 127) / 128, 256, 0, stream>>>(
        xb, WTs + (size_t)h * D * D, WTd + (size_t)h * D * D,
        b_src + (size_t)h * D, b_dest + (size_t)h * D, s_b, t_b, N);
    aggregate_kernel<<<(N + 3) / 4, 256, 0, stream>>>(
        s_b, t_b, xb, totc, pk,
        ee + (size_t)h * NE * D, ln_g + (size_t)h * D, ln_b + (size_t)h * D,
        out, (h < HOPS - 1) ? 1 : 0, N);
  }
}